// Round 6
// baseline (499.118 us; speedup 1.0000x reference)
//
#include <hip/hip_runtime.h>
#include <math.h>

// Problem shape (fixed by setup_inputs)
#define BATCH 32
#define HH 768
#define WW 768
#define NBLK 2048   // 32 batches x 8 region-rows x 8 row-chunks

typedef float v4f __attribute__((ext_vector_type(4)));

// ws layout (bytes) — first 8704 bytes zeroed via hipMemsetAsync:
//   [0,256)    : 64 float sq buckets (atomicAdd accumulation)
//   [256,260)  : unsigned arrival counter
//   [512,8704) : 2048 float level-3 region diffs (atomicAdd accumulation)

__global__ __launch_bounds__(256) void fused_loss(
    const float* __restrict__ pred, const float* __restrict__ gt,
    const float* __restrict__ rgb, const float* __restrict__ th,
    float* __restrict__ out, float* __restrict__ ws)
{
    float* sqb = ws;                        // [64]
    unsigned* ctr = (unsigned*)(ws + 64);   // byte 256
    float* dreg = ws + 128;                 // [2048] at byte 512

    const int bid   = blockIdx.x;           // b*64 + ri*8 + chunk
    const int b     = bid >> 6;
    const int ri    = (bid >> 3) & 7;
    const int chunk = bid & 7;
    const size_t base = (size_t)b * (HH * WW) + (size_t)(ri * 96 + chunk * 12) * WW;

    const int t = threadIdx.x;
    const int g = t >> 5;                   // column stripe 0..7
    const int l = t & 31;

    const float* pb = pred + base + g * 96;
    const float* gb = gt   + base + g * 96;

    // stripe = 12 rows x 24 float4; lane l handles q = l + 32k, k=0..8
    float sq = 0.f, ds = 0.f;
    #pragma unroll
    for (int k = 0; k < 9; ++k) {
        const int q   = l + 32 * k;         // 0..287
        const int row = q / 24;
        const int c   = q - row * 24;
        const v4f p  = __builtin_nontemporal_load((const v4f*)(pb + row * WW + c * 4));
        const v4f gg = __builtin_nontemporal_load((const v4f*)(gb + row * WW + c * 4));
        const float dx = p[0] - gg[0], dy = p[1] - gg[1];
        const float dz = p[2] - gg[2], dw = p[3] - gg[3];
        sq += (dx * dx + dy * dy) + (dz * dz + dw * dw);
        ds += (dx + dy) + (dz + dw);
    }

    // ds: reduce within the 32-lane stripe group; sq: across the 64-lane wave
    #pragma unroll
    for (int o = 16; o > 0; o >>= 1) ds += __shfl_down(ds, o, 64);
    #pragma unroll
    for (int o = 32; o > 0; o >>= 1) sq += __shfl_down(sq, o, 64);

    if (l == 0)        atomicAdd(&dreg[((b << 3) + ri) * 8 + g], ds);
    if ((t & 63) == 0) atomicAdd(&sqb[bid & 63], sq);

    // ---- arrival: last block runs the tail ----
    __threadfence();
    __syncthreads();
    __shared__ unsigned s_last;
    if (t == 0) s_last = (atomicAdd(ctr, 1u) == (unsigned)(NBLK - 1)) ? 1u : 0u;
    __syncthreads();
    if (s_last == 0) return;
    __threadfence();

    // ---- tail: final loss (256 threads of the last block) ----
    __shared__ float d[2048];        // level-3 region diffs (b*64 + ri*8 + rj)
    __shared__ float d2[BATCH * 16];
    __shared__ float d1[BATCH * 4];
    __shared__ float redbuf[4 * 6];

    float s_sq = (t < 64) ? sqb[t] : 0.f;

    float l3 = 0.f;
    #pragma unroll
    for (int k = 0; k < 2; ++k) {
        const int i4 = t + 256 * k;          // float4 index, 512 total
        const v4f v = ((const v4f*)dreg)[i4];
        d[4 * i4 + 0] = v[0]; d[4 * i4 + 1] = v[1];
        d[4 * i4 + 2] = v[2]; d[4 * i4 + 3] = v[3];
        l3 += (fabsf(v[0]) + fabsf(v[1])) + (fabsf(v[2]) + fabsf(v[3]));
    }
    __syncthreads();

    // level 2: 32 batches x 16 cells, 2x2 aggregation of level-3
    float l2 = 0.f;
    #pragma unroll
    for (int k = 0; k < 2; ++k) {
        const int i = t + 256 * k;
        const int bb = i >> 4, r2 = i & 15;
        const int i2 = r2 >> 2, j2 = r2 & 3;
        const float* db = d + bb * 64;
        const float v = (db[(2 * i2) * 8 + 2 * j2]     + db[(2 * i2) * 8 + 2 * j2 + 1])
                      + (db[(2 * i2 + 1) * 8 + 2 * j2] + db[(2 * i2 + 1) * 8 + 2 * j2 + 1]);
        d2[i] = v;
        l2 += fabsf(v);
    }
    __syncthreads();

    // level 1: 32 x 4 cells
    float l1 = 0.f;
    if (t < BATCH * 4) {
        const int bb = t >> 2, r1 = t & 3;
        const int i1 = r1 >> 1, j1 = r1 & 1;
        const float* db = d2 + bb * 16;
        const float v = (db[(2 * i1) * 4 + 2 * j1]     + db[(2 * i1) * 4 + 2 * j1 + 1])
                      + (db[(2 * i1 + 1) * 4 + 2 * j1] + db[(2 * i1 + 1) * 4 + 2 * j1 + 1]);
        d1[t] = v;
        l1 = fabsf(v);
    }
    __syncthreads();

    // per-batch count diff + domain CE
    float cnt = 0.f, dom = 0.f;
    if (t < BATCH) {
        const float c = (d1[t * 4] + d1[t * 4 + 1]) + (d1[t * 4 + 2] + d1[t * 4 + 3]);
        cnt = fabsf(c);
        const float x0 = rgb[t * 2], x1 = rgb[t * 2 + 1];
        const float mx = fmaxf(x0, x1);
        dom  = (mx + logf(expf(x0 - mx) + expf(x1 - mx))) - x0;
        const float y0 = th[t * 2], y1 = th[t * 2 + 1];
        const float my = fmaxf(y0, y1);
        dom += (my + logf(expf(y0 - my) + expf(y1 - my))) - y1;
    }

    // fused 6-value reduction: wave shuffle, then 4-wave LDS combine
    float vals[6] = {s_sq, l3, l2, l1, cnt, dom};
    #pragma unroll
    for (int off = 32; off > 0; off >>= 1) {
        #pragma unroll
        for (int j = 0; j < 6; ++j) vals[j] += __shfl_down(vals[j], off, 64);
    }
    const int wave = t >> 6;
    if ((t & 63) == 0) {
        #pragma unroll
        for (int j = 0; j < 6; ++j) redbuf[wave * 6 + j] = vals[j];
    }
    __syncthreads();
    if (t == 0) {
        float S[6];
        #pragma unroll
        for (int j = 0; j < 6; ++j)
            S[j] = (redbuf[j] + redbuf[6 + j]) + (redbuf[12 + j] + redbuf[18 + j]);
        const float density  = S[0] / (float)((size_t)BATCH * HH * WW);
        const float count_l  = S[4] / (float)BATCH;
        const float regional = ((S[3] + S[2] + S[1]) / (float)BATCH) / 192.0f;
        const float domain   = S[5] / 64.0f;
        out[0] = 100.0f * density + 0.001f * count_l + 1.0f * regional + 0.5f * domain;
    }
}

extern "C" void kernel_launch(void* const* d_in, const int* in_sizes, int n_in,
                              void* d_out, int out_size, void* d_ws, size_t ws_size,
                              hipStream_t stream) {
    const float* pred = (const float*)d_in[0];
    const float* gt   = (const float*)d_in[1];
    const float* rgb  = (const float*)d_in[2];
    const float* th   = (const float*)d_in[3];
    float* out = (float*)d_out;
    float* ws  = (float*)d_ws;

    // zero the accumulators + arrival counter (ws is poisoned 0xAA pre-launch)
    (void)hipMemsetAsync(d_ws, 0, 8704, stream);
    fused_loss<<<NBLK, 256, 0, stream>>>(pred, gt, rgb, th, out, ws);
}